// Round 1
// baseline (235.540 us; speedup 1.0000x reference)
//
#include <hip/hip_runtime.h>
#include <math.h>

#define BQ 8
#define CC 256
#define HH 64
#define WW 64
#define LL 4096
#define AH 8
#define NSAMP 4
#define DD 32

// GEMM: out[b][o][l] = sum_c W[o][c] * X[b][c][l] + bias[o]
// X layout: [B][C][L] (channel-major, l contiguous)
// EPI 0: out layout [B][O][L]
// EPI 1: v_samp layout [(b*A + o/32)][l][o%32]  (for the sampler)
template<int EPI>
__global__ __launch_bounds__(256, 2)
void gemm_f32(const float* __restrict__ X, const float* __restrict__ Wm,
              const float* __restrict__ bias, float* __restrict__ out, int O)
{
    __shared__ float w_s[64][36];    // 64 o-rows x 32 k (+4 pad)
    __shared__ float x_s[32][128];   // 32 k-rows x 128 l

    const int lb = blockIdx.x;   // L/128 tiles
    const int ob = blockIdx.y;   // O/64 tiles
    const int b  = blockIdx.z;
    const int t  = threadIdx.x;
    const int tx = t & 31;       // l group (0..31)
    const int ty = t >> 5;       // o group (0..7)
    const int l0 = tx * 4;
    const int o0 = ty * 8;

    float acc[8][4];
#pragma unroll
    for (int i = 0; i < 8; ++i)
#pragma unroll
        for (int j = 0; j < 4; ++j) acc[i][j] = 0.f;

    const float* Xb = X + (size_t)b * CC * LL + lb * 128;

    for (int k0 = 0; k0 < CC; k0 += 32) {
        // stage W chunk: rows 64 (o), cols 32 (k)
        {
            int o  = t >> 2;
            int cs = (t & 3) * 8;
            int og = ob * 64 + o;
            float4 v0, v1;
            if (og < O) {
                const float* wp = Wm + (size_t)og * CC + k0 + cs;
                v0 = *(const float4*)wp;
                v1 = *(const float4*)(wp + 4);
            } else {
                v0 = make_float4(0.f, 0.f, 0.f, 0.f);
                v1 = v0;
            }
            *(float4*)&w_s[o][cs]     = v0;
            *(float4*)&w_s[o][cs + 4] = v1;
        }
        // stage X chunk: rows 32 (k), cols 128 (l)
#pragma unroll
        for (int i = 0; i < 4; ++i) {
            int f4 = i * 256 + t;       // float4 slot in [32][32]
            int kk = f4 >> 5;
            int l4 = f4 & 31;
            *(float4*)&x_s[kk][l4 * 4] =
                *(const float4*)(Xb + (size_t)(k0 + kk) * LL + l4 * 4);
        }
        __syncthreads();

#pragma unroll
        for (int ks = 0; ks < 32; ks += 4) {
            float4 xq[4];
#pragma unroll
            for (int k = 0; k < 4; ++k) xq[k] = *(const float4*)&x_s[ks + k][l0];
#pragma unroll
            for (int i = 0; i < 8; ++i) {
                float4 wq = *(const float4*)&w_s[o0 + i][ks];
                acc[i][0] += wq.x * xq[0].x; acc[i][1] += wq.x * xq[0].y;
                acc[i][2] += wq.x * xq[0].z; acc[i][3] += wq.x * xq[0].w;
                acc[i][0] += wq.y * xq[1].x; acc[i][1] += wq.y * xq[1].y;
                acc[i][2] += wq.y * xq[1].z; acc[i][3] += wq.y * xq[1].w;
                acc[i][0] += wq.z * xq[2].x; acc[i][1] += wq.z * xq[2].y;
                acc[i][2] += wq.z * xq[2].z; acc[i][3] += wq.z * xq[2].w;
                acc[i][0] += wq.w * xq[3].x; acc[i][1] += wq.w * xq[3].y;
                acc[i][2] += wq.w * xq[3].z; acc[i][3] += wq.w * xq[3].w;
            }
        }
        __syncthreads();
    }

    const int og0 = ob * 64 + o0;
    const int lg0 = lb * 128 + l0;
    if (EPI == 0) {
#pragma unroll
        for (int i = 0; i < 8; ++i) {
            int og = og0 + i;
            if (og < O) {
                float bs = bias[og];
                float4 r = make_float4(acc[i][0] + bs, acc[i][1] + bs,
                                       acc[i][2] + bs, acc[i][3] + bs);
                *(float4*)(out + ((size_t)b * O + og) * LL + lg0) = r;
            }
        }
    } else {
        // v layout [(b*A+a)][l][32]; og0 is a multiple of 8 -> one head
        int a  = og0 >> 5;
        int d0 = og0 & 31;
        float bs[8];
#pragma unroll
        for (int i = 0; i < 8; ++i) bs[i] = bias[og0 + i];
#pragma unroll
        for (int j = 0; j < 4; ++j) {
            float4 r0 = make_float4(acc[0][j] + bs[0], acc[1][j] + bs[1],
                                    acc[2][j] + bs[2], acc[3][j] + bs[3]);
            float4 r1 = make_float4(acc[4][j] + bs[4], acc[5][j] + bs[5],
                                    acc[6][j] + bs[6], acc[7][j] + bs[7]);
            float* op = out + ((size_t)(b * AH + a) * LL + lg0 + j) * DD + d0;
            *(float4*)op       = r0;
            *(float4*)(op + 4) = r1;
        }
    }
}

// softmax over N=4 per (b,l,a) + sampling positions (pixel-normalized later)
__global__ __launch_bounds__(256)
void prep_kernel(const float* __restrict__ log_att,  // [B][32][L]
                 const float* __restrict__ log_off,  // [B][64][L]
                 float* __restrict__ attn4,          // [B*A*L] float4
                 float* __restrict__ pos4)           // [B*A*L*2] float4
{
    int gid = blockIdx.x * 256 + threadIdx.x;   // over B*L
    int b = gid >> 12;
    int l = gid & 4095;
    int i = l >> 6, j = l & 63;
    float ry = (i + 0.5f) * (2.0f / 63.0f) - 1.0f;
    float rx = (j + 0.5f) * (2.0f / 63.0f) - 1.0f;
    const float* la = log_att + (size_t)b * 32 * LL + l;
    const float* lo = log_off + (size_t)b * 64 * LL + l;
#pragma unroll
    for (int a = 0; a < AH; ++a) {
        float e[4];
        float m = -1e30f;
#pragma unroll
        for (int n = 0; n < 4; ++n) {
            e[n] = la[(size_t)(a * 4 + n) * LL];
            m = fmaxf(m, e[n]);
        }
        float s = 0.f;
#pragma unroll
        for (int n = 0; n < 4; ++n) { e[n] = expf(e[n] - m); s += e[n]; }
        float inv = 1.0f / s;
        size_t base = (size_t)(b * AH + a) * LL + l;
        *(float4*)(attn4 + base * 4) =
            make_float4(e[0] * inv, e[1] * inv, e[2] * inv, e[3] * inv);
        float py[4], px[4];
#pragma unroll
        for (int n = 0; n < 4; ++n) {
            py[n] = ry + lo[(size_t)(a * 8 + n * 2 + 0) * LL];
            px[n] = rx + lo[(size_t)(a * 8 + n * 2 + 1) * LL];
        }
        *(float4*)(pos4 + base * 8)     = make_float4(py[0], px[0], py[1], px[1]);
        *(float4*)(pos4 + base * 8 + 4) = make_float4(py[2], px[2], py[3], px[3]);
    }
}

// bilinear sample + attention-weighted aggregation
// grid: (L/64, B*A); 4 threads per point, 8 channels each
__global__ __launch_bounds__(256)
void sample_kernel(const float* __restrict__ v_samp,  // [(B*A)][L][32]
                   const float* __restrict__ attn4,
                   const float* __restrict__ pos4,
                   float* __restrict__ agg)           // [B][C][L]
{
    int t  = threadIdx.x;
    int lt = blockIdx.x;
    int ba = blockIdx.y;
    int l  = lt * 64 + (t >> 2);
    int d0 = (t & 3) * 8;
    size_t base = (size_t)ba * LL + l;
    float4 at  = *(const float4*)(attn4 + base * 4);
    float4 p01 = *(const float4*)(pos4 + base * 8);
    float4 p23 = *(const float4*)(pos4 + base * 8 + 4);
    float attn[4] = {at.x, at.y, at.z, at.w};
    float pyy[4]  = {p01.x, p01.z, p23.x, p23.z};
    float pxx[4]  = {p01.y, p01.w, p23.y, p23.w};

    float acc[8];
#pragma unroll
    for (int q = 0; q < 8; ++q) acc[q] = 0.f;

    const float* vb = v_samp + (size_t)ba * LL * DD;
#pragma unroll
    for (int n = 0; n < 4; ++n) {
        float y = (pyy[n] + 1.0f) * 0.5f * 63.0f;
        float x = (pxx[n] + 1.0f) * 0.5f * 63.0f;
        float yf = floorf(y), xf = floorf(x);
        int y0i = (int)yf, x0i = (int)xf;
        float fy = y - yf, fx = x - xf;
        float wts[4] = {(1.f - fy) * (1.f - fx), (1.f - fy) * fx,
                        fy * (1.f - fx),         fy * fx};
        int yy[4] = {y0i, y0i, y0i + 1, y0i + 1};
        int xx[4] = {x0i, x0i + 1, x0i, x0i + 1};
#pragma unroll
        for (int c2 = 0; c2 < 4; ++c2) {
            int yc = yy[c2], xc = xx[c2];
            if (yc >= 0 && yc < HH && xc >= 0 && xc < WW) {
                float w = attn[n] * wts[c2];
                const float* vp = vb + (size_t)(yc * WW + xc) * DD + d0;
                float4 v0 = *(const float4*)vp;
                float4 v1 = *(const float4*)(vp + 4);
                acc[0] += w * v0.x; acc[1] += w * v0.y;
                acc[2] += w * v0.z; acc[3] += w * v0.w;
                acc[4] += w * v1.x; acc[5] += w * v1.y;
                acc[6] += w * v1.z; acc[7] += w * v1.w;
            }
        }
    }
    int b = ba >> 3, a = ba & 7;
    float* ag = agg + ((size_t)b * CC + a * DD + d0) * LL + l;
#pragma unroll
    for (int q = 0; q < 8; ++q) ag[(size_t)q * LL] = acc[q];
}

extern "C" void kernel_launch(void* const* d_in, const int* in_sizes, int n_in,
                              void* d_out, int out_size, void* d_ws, size_t ws_size,
                              hipStream_t stream) {
    const float* x     = (const float*)d_in[0];
    const float* w_att = (const float*)d_in[1];
    const float* b_att = (const float*)d_in[2];
    const float* w_off = (const float*)d_in[3];
    const float* b_off = (const float*)d_in[4];
    const float* w_v   = (const float*)d_in[5];
    const float* b_v   = (const float*)d_in[6];
    const float* w_out = (const float*)d_in[7];
    const float* b_out = (const float*)d_in[8];
    float* out = (float*)d_out;

    float* ws      = (float*)d_ws;
    float* log_att = ws;                                  // B*32*L
    float* log_off = log_att + (size_t)BQ * 32 * LL;      // B*64*L
    float* attn4   = log_off + (size_t)BQ * 64 * LL;      // B*A*L*4
    float* pos4    = attn4   + (size_t)BQ * AH * LL * 4;  // B*A*L*8
    float* agg     = pos4    + (size_t)BQ * AH * LL * 8;  // B*C*L
    float* v_samp  = out;  // reuse d_out as scratch for v (exact size, dead
                           // before final GEMM writes d_out)

    dim3 blk(256);
    gemm_f32<0><<<dim3(32, 1, BQ), blk, 0, stream>>>(x, w_att, b_att, log_att, 32);
    gemm_f32<0><<<dim3(32, 1, BQ), blk, 0, stream>>>(x, w_off, b_off, log_off, 64);
    gemm_f32<1><<<dim3(32, 4, BQ), blk, 0, stream>>>(x, w_v, b_v, v_samp, 256);
    prep_kernel<<<dim3(128), blk, 0, stream>>>(log_att, log_off, attn4, pos4);
    sample_kernel<<<dim3(64, 64), blk, 0, stream>>>(v_samp, attn4, pos4, agg);
    gemm_f32<0><<<dim3(32, 4, BQ), blk, 0, stream>>>(agg, w_out, b_out, out, 256);
}

// Round 2
// 154.057 us; speedup vs baseline: 1.5289x; 1.5289x over previous
//
#include <hip/hip_runtime.h>
#include <math.h>
#include <stdint.h>

#define BQ 8
#define CC 256
#define HH 64
#define WW 64
#define LL 4096
#define AH 8
#define DD 32

typedef __attribute__((ext_vector_type(4))) float f32x4;
typedef __attribute__((ext_vector_type(8))) short short8;

__device__ inline uint32_t pk_bf16(float a, float b) {
    uint32_t r;
    asm("v_cvt_pk_bf16_f32 %0, %1, %2" : "=v"(r) : "v"(a), "v"(b));
    return r;
}

// ---------------------------------------------------------------------------
// bf16 MFMA GEMM: out[b][o][l] = sum_k W[o][k] * X[b][k][l] + bias[o]
// X: [B][256][4096] fp32 (k-major rows, l contiguous) -> transpose-staged
// W: [256][256] fp32 (k contiguous)
// 128x128 tile, BK=64, 4 waves, each wave 64x64 (4x4 16x16x32 frags).
// LDS tiles [row][64 bf16] = 128B rows, 16B-slot XOR swizzle: slot ^= row&7.
// EPI 0: out [B][O][L].  EPI 1: v_samp [(b*8+o/32)][l][o%32].
// ---------------------------------------------------------------------------
template<int EPI>
__global__ __launch_bounds__(256, 2)
void gemm_bf16(const float* __restrict__ X, const float* __restrict__ Wm,
               const float* __restrict__ bias, float* __restrict__ out)
{
    __shared__ uint32_t a_s[128 * 32];   // 16 KB
    __shared__ uint32_t b_s[128 * 32];   // 16 KB

    const int nb = blockIdx.x;           // 0..255 (b*32 + l-tile)
    const int b  = nb >> 5;
    const int lb = nb & 31;
    const int ob = blockIdx.y;           // 0..1
    const int t  = threadIdx.x;
    const int lane = t & 63;
    const int wv = t >> 6;
    const int wm = wv >> 1, wn = wv & 1;

    // A staging: thread covers (row a_r0 + i*16, float4 index a_f4) of W tile
    const int a_f4 = t & 15;
    const int a_r0 = t >> 4;
    // B staging: thread covers 8 k-rows (b_kb*8+i) x 4 l (b_l0*4+j) of X tile
    const int b_kb = t & 7;
    const int b_l0 = t >> 3;             // 0..31

    const float* Ap = Wm + (size_t)(ob * 128 + a_r0) * CC + a_f4 * 4;
    const float* Bp = X + ((size_t)b * CC + b_kb * 8) * LL + lb * 128 + b_l0 * 4;

    f32x4 acc[4][4];
#pragma unroll
    for (int i = 0; i < 4; ++i)
#pragma unroll
        for (int j = 0; j < 4; ++j) acc[i][j] = (f32x4)0.0f;

    for (int kc = 0; kc < 4; ++kc) {
        // ---- global loads (fp32) ----
        float4 av[8], bv[8];
        const float* ap = Ap + kc * 64;
        const float* bp = Bp + (size_t)(kc * 64) * LL;
#pragma unroll
        for (int i = 0; i < 8; ++i)
            av[i] = *(const float4*)(ap + (size_t)i * 16 * CC);
#pragma unroll
        for (int i = 0; i < 8; ++i)
            bv[i] = *(const float4*)(bp + (size_t)i * LL);

        // ---- convert + LDS write: A rows a_r0+i*16, slot (a_f4>>1)^(r&7) ----
#pragma unroll
        for (int i = 0; i < 8; ++i) {
            int r = a_r0 + i * 16;
            uint32_t lo = pk_bf16(av[i].x, av[i].y);
            uint32_t hi = pk_bf16(av[i].z, av[i].w);
            int slot = (a_f4 >> 1) ^ (r & 7);
            *(uint2*)&a_s[r * 32 + (slot << 2) + ((a_f4 & 1) << 1)] =
                make_uint2(lo, hi);
        }
        // ---- B transpose: row l = b_l0*4+j gets k = kc*64 + b_kb*8 .. +7 ----
#pragma unroll
        for (int j = 0; j < 4; ++j) {
            int l = b_l0 * 4 + j;
            uint32_t w0 = pk_bf16(((const float*)&bv[0])[j], ((const float*)&bv[1])[j]);
            uint32_t w1 = pk_bf16(((const float*)&bv[2])[j], ((const float*)&bv[3])[j]);
            uint32_t w2 = pk_bf16(((const float*)&bv[4])[j], ((const float*)&bv[5])[j]);
            uint32_t w3 = pk_bf16(((const float*)&bv[6])[j], ((const float*)&bv[7])[j]);
            int slot = b_kb ^ (l & 7);
            *(uint4*)&b_s[l * 32 + (slot << 2)] = make_uint4(w0, w1, w2, w3);
        }
        __syncthreads();

        // ---- MFMA: 2 k-steps of 32 ----
#pragma unroll
        for (int ks = 0; ks < 2; ++ks) {
            int ag = ks * 4 + (lane >> 4);
            short8 af[4], bf[4];
#pragma unroll
            for (int mf = 0; mf < 4; ++mf) {
                int r = wm * 64 + mf * 16 + (lane & 15);
                af[mf] = *(const short8*)&a_s[r * 32 + ((ag ^ (r & 7)) << 2)];
            }
#pragma unroll
            for (int nf = 0; nf < 4; ++nf) {
                int r = wn * 64 + nf * 16 + (lane & 15);
                bf[nf] = *(const short8*)&b_s[r * 32 + ((ag ^ (r & 7)) << 2)];
            }
#pragma unroll
            for (int mf = 0; mf < 4; ++mf)
#pragma unroll
                for (int nf = 0; nf < 4; ++nf)
                    acc[mf][nf] = __builtin_amdgcn_mfma_f32_16x16x32_bf16(
                        af[mf], bf[nf], acc[mf][nf], 0, 0, 0);
        }
        __syncthreads();
    }

    const int l_base = lb * 128 + wn * 64 + (lane & 15);
    const int o_base = ob * 128 + wm * 64 + ((lane >> 4) << 2);
    if (EPI == 0) {
#pragma unroll
        for (int mf = 0; mf < 4; ++mf) {
            int o0 = o_base + mf * 16;
            float4 bs = *(const float4*)(bias + o0);
#pragma unroll
            for (int nf = 0; nf < 4; ++nf) {
                int l = l_base + nf * 16;
                float* op = out + ((size_t)b * CC + o0) * LL + l;
                op[(size_t)0 * LL] = acc[mf][nf][0] + bs.x;
                op[(size_t)1 * LL] = acc[mf][nf][1] + bs.y;
                op[(size_t)2 * LL] = acc[mf][nf][2] + bs.z;
                op[(size_t)3 * LL] = acc[mf][nf][3] + bs.w;
            }
        }
    } else {
#pragma unroll
        for (int mf = 0; mf < 4; ++mf) {
            int o0 = o_base + mf * 16;
            float4 bs = *(const float4*)(bias + o0);
            int a_h = o0 >> 5;
            int d0 = o0 & 31;
#pragma unroll
            for (int nf = 0; nf < 4; ++nf) {
                int l = l_base + nf * 16;
                float4 r = make_float4(acc[mf][nf][0] + bs.x, acc[mf][nf][1] + bs.y,
                                       acc[mf][nf][2] + bs.z, acc[mf][nf][3] + bs.w);
                *(float4*)(out + ((size_t)(b * AH + a_h) * LL + l) * DD + d0) = r;
            }
        }
    }
}

// ---------------------------------------------------------------------------
// fp32 GEMM (kept for att/off heads: position-critical precision)
// ---------------------------------------------------------------------------
template<int EPI>
__global__ __launch_bounds__(256, 2)
void gemm_f32(const float* __restrict__ X, const float* __restrict__ Wm,
              const float* __restrict__ bias, float* __restrict__ out, int O)
{
    __shared__ float w_s[64][36];
    __shared__ float x_s[32][128];

    const int lb = blockIdx.x;
    const int ob = blockIdx.y;
    const int b  = blockIdx.z;
    const int t  = threadIdx.x;
    const int tx = t & 31;
    const int ty = t >> 5;
    const int l0 = tx * 4;
    const int o0 = ty * 8;

    float acc[8][4];
#pragma unroll
    for (int i = 0; i < 8; ++i)
#pragma unroll
        for (int j = 0; j < 4; ++j) acc[i][j] = 0.f;

    const float* Xb = X + (size_t)b * CC * LL + lb * 128;

    for (int k0 = 0; k0 < CC; k0 += 32) {
        {
            int o  = t >> 2;
            int cs = (t & 3) * 8;
            int og = ob * 64 + o;
            float4 v0, v1;
            if (og < O) {
                const float* wp = Wm + (size_t)og * CC + k0 + cs;
                v0 = *(const float4*)wp;
                v1 = *(const float4*)(wp + 4);
            } else {
                v0 = make_float4(0.f, 0.f, 0.f, 0.f);
                v1 = v0;
            }
            *(float4*)&w_s[o][cs]     = v0;
            *(float4*)&w_s[o][cs + 4] = v1;
        }
#pragma unroll
        for (int i = 0; i < 4; ++i) {
            int f4 = i * 256 + t;
            int kk = f4 >> 5;
            int l4 = f4 & 31;
            *(float4*)&x_s[kk][l4 * 4] =
                *(const float4*)(Xb + (size_t)(k0 + kk) * LL + l4 * 4);
        }
        __syncthreads();

#pragma unroll
        for (int ks = 0; ks < 32; ks += 4) {
            float4 xq[4];
#pragma unroll
            for (int k = 0; k < 4; ++k) xq[k] = *(const float4*)&x_s[ks + k][l0];
#pragma unroll
            for (int i = 0; i < 8; ++i) {
                float4 wq = *(const float4*)&w_s[o0 + i][ks];
                acc[i][0] += wq.x * xq[0].x; acc[i][1] += wq.x * xq[0].y;
                acc[i][2] += wq.x * xq[0].z; acc[i][3] += wq.x * xq[0].w;
                acc[i][0] += wq.y * xq[1].x; acc[i][1] += wq.y * xq[1].y;
                acc[i][2] += wq.y * xq[1].z; acc[i][3] += wq.y * xq[1].w;
                acc[i][0] += wq.z * xq[2].x; acc[i][1] += wq.z * xq[2].y;
                acc[i][2] += wq.z * xq[2].z; acc[i][3] += wq.z * xq[2].w;
                acc[i][0] += wq.w * xq[3].x; acc[i][1] += wq.w * xq[3].y;
                acc[i][2] += wq.w * xq[3].z; acc[i][3] += wq.w * xq[3].w;
            }
        }
        __syncthreads();
    }

    const int og0 = ob * 64 + o0;
    const int lg0 = lb * 128 + l0;
#pragma unroll
    for (int i = 0; i < 8; ++i) {
        int og = og0 + i;
        if (og < O) {
            float bs = bias[og];
            float4 r = make_float4(acc[i][0] + bs, acc[i][1] + bs,
                                   acc[i][2] + bs, acc[i][3] + bs);
            *(float4*)(out + ((size_t)b * O + og) * LL + lg0) = r;
        }
    }
}

// softmax over N=4 per (b,l,a) + sampling positions
__global__ __launch_bounds__(256)
void prep_kernel(const float* __restrict__ log_att,  // [B][32][L]
                 const float* __restrict__ log_off,  // [B][64][L]
                 float* __restrict__ attn4,
                 float* __restrict__ pos4)
{
    int gid = blockIdx.x * 256 + threadIdx.x;
    int b = gid >> 12;
    int l = gid & 4095;
    int i = l >> 6, j = l & 63;
    float ry = (i + 0.5f) * (2.0f / 63.0f) - 1.0f;
    float rx = (j + 0.5f) * (2.0f / 63.0f) - 1.0f;
    const float* la = log_att + (size_t)b * 32 * LL + l;
    const float* lo = log_off + (size_t)b * 64 * LL + l;
#pragma unroll
    for (int a = 0; a < AH; ++a) {
        float e[4];
        float m = -1e30f;
#pragma unroll
        for (int n = 0; n < 4; ++n) {
            e[n] = la[(size_t)(a * 4 + n) * LL];
            m = fmaxf(m, e[n]);
        }
        float s = 0.f;
#pragma unroll
        for (int n = 0; n < 4; ++n) { e[n] = expf(e[n] - m); s += e[n]; }
        float inv = 1.0f / s;
        size_t base = (size_t)(b * AH + a) * LL + l;
        *(float4*)(attn4 + base * 4) =
            make_float4(e[0] * inv, e[1] * inv, e[2] * inv, e[3] * inv);
        float py[4], px[4];
#pragma unroll
        for (int n = 0; n < 4; ++n) {
            py[n] = ry + lo[(size_t)(a * 8 + n * 2 + 0) * LL];
            px[n] = rx + lo[(size_t)(a * 8 + n * 2 + 1) * LL];
        }
        *(float4*)(pos4 + base * 8)     = make_float4(py[0], px[0], py[1], px[1]);
        *(float4*)(pos4 + base * 8 + 4) = make_float4(py[2], px[2], py[3], px[3]);
    }
}

// bilinear sample + attention-weighted aggregation
__global__ __launch_bounds__(256)
void sample_kernel(const float* __restrict__ v_samp,  // [(B*A)][L][32]
                   const float* __restrict__ attn4,
                   const float* __restrict__ pos4,
                   float* __restrict__ agg)           // [B][C][L]
{
    int t  = threadIdx.x;
    int lt = blockIdx.x;
    int ba = blockIdx.y;
    int l  = lt * 64 + (t >> 2);
    int d0 = (t & 3) * 8;
    size_t base = (size_t)ba * LL + l;
    float4 at  = *(const float4*)(attn4 + base * 4);
    float4 p01 = *(const float4*)(pos4 + base * 8);
    float4 p23 = *(const float4*)(pos4 + base * 8 + 4);
    float attn[4] = {at.x, at.y, at.z, at.w};
    float pyy[4]  = {p01.x, p01.z, p23.x, p23.z};
    float pxx[4]  = {p01.y, p01.w, p23.y, p23.w};

    float acc[8];
#pragma unroll
    for (int q = 0; q < 8; ++q) acc[q] = 0.f;

    const float* vb = v_samp + (size_t)ba * LL * DD;
#pragma unroll
    for (int n = 0; n < 4; ++n) {
        float y = (pyy[n] + 1.0f) * 0.5f * 63.0f;
        float x = (pxx[n] + 1.0f) * 0.5f * 63.0f;
        float yf = floorf(y), xf = floorf(x);
        int y0i = (int)yf, x0i = (int)xf;
        float fy = y - yf, fx = x - xf;
        float wts[4] = {(1.f - fy) * (1.f - fx), (1.f - fy) * fx,
                        fy * (1.f - fx),         fy * fx};
        int yy[4] = {y0i, y0i, y0i + 1, y0i + 1};
        int xx[4] = {x0i, x0i + 1, x0i, x0i + 1};
#pragma unroll
        for (int c2 = 0; c2 < 4; ++c2) {
            int yc = yy[c2], xc = xx[c2];
            if (yc >= 0 && yc < HH && xc >= 0 && xc < WW) {
                float w = attn[n] * wts[c2];
                const float* vp = vb + (size_t)(yc * WW + xc) * DD + d0;
                float4 v0 = *(const float4*)vp;
                float4 v1 = *(const float4*)(vp + 4);
                acc[0] += w * v0.x; acc[1] += w * v0.y;
                acc[2] += w * v0.z; acc[3] += w * v0.w;
                acc[4] += w * v1.x; acc[5] += w * v1.y;
                acc[6] += w * v1.z; acc[7] += w * v1.w;
            }
        }
    }
    int b = ba >> 3, a = ba & 7;
    float* ag = agg + ((size_t)b * CC + a * DD + d0) * LL + l;
#pragma unroll
    for (int q = 0; q < 8; ++q) ag[(size_t)q * LL] = acc[q];
}

extern "C" void kernel_launch(void* const* d_in, const int* in_sizes, int n_in,
                              void* d_out, int out_size, void* d_ws, size_t ws_size,
                              hipStream_t stream) {
    const float* x     = (const float*)d_in[0];
    const float* w_att = (const float*)d_in[1];
    const float* b_att = (const float*)d_in[2];
    const float* w_off = (const float*)d_in[3];
    const float* b_off = (const float*)d_in[4];
    const float* w_v   = (const float*)d_in[5];
    const float* b_v   = (const float*)d_in[6];
    const float* w_out = (const float*)d_in[7];
    const float* b_out = (const float*)d_in[8];
    float* out = (float*)d_out;

    float* ws      = (float*)d_ws;
    float* log_att = ws;                                  // B*32*L
    float* log_off = log_att + (size_t)BQ * 32 * LL;      // B*64*L
    float* attn4   = log_off + (size_t)BQ * 64 * LL;      // B*A*L*4
    float* pos4    = attn4   + (size_t)BQ * AH * LL * 4;  // B*A*L*8
    float* agg     = pos4    + (size_t)BQ * AH * LL * 8;  // B*C*L
    float* v_samp  = out;  // d_out reused as scratch for v (dead before final GEMM)

    dim3 blk(256);
    gemm_f32<0><<<dim3(32, 1, BQ), blk, 0, stream>>>(x, w_att, b_att, log_att, 32);
    gemm_f32<0><<<dim3(32, 1, BQ), blk, 0, stream>>>(x, w_off, b_off, log_off, 64);
    gemm_bf16<1><<<dim3(256, 2), blk, 0, stream>>>(x, w_v, b_v, v_samp);
    prep_kernel<<<dim3(128), blk, 0, stream>>>(log_att, log_off, attn4, pos4);
    sample_kernel<<<dim3(64, 64), blk, 0, stream>>>(v_samp, attn4, pos4, agg);
    gemm_bf16<0><<<dim3(256, 2), blk, 0, stream>>>(agg, w_out, b_out, out);
}

// Round 3
// 117.673 us; speedup vs baseline: 2.0016x; 1.3092x over previous
//
#include <hip/hip_runtime.h>
#include <math.h>
#include <stdint.h>

#define BQ 8
#define CC 256
#define HH 64
#define WW 64
#define LL 4096
#define AH 8
#define DD 32

typedef __attribute__((ext_vector_type(4))) float f32x4;
typedef __attribute__((ext_vector_type(8))) short short8;

__device__ inline uint32_t pk_bf16(float a, float b) {
    uint32_t r;
    asm("v_cvt_pk_bf16_f32 %0, %1, %2" : "=v"(r) : "v"(a), "v"(b));
    return r;
}

// ---------------------------------------------------------------------------
// bf16 MFMA GEMM: out[b][o][l] = sum_k W[o][k] * X[b][k][l] + bias[o]
// 128x128 tile, BK=64, 4 waves, each wave 64x64 (4x4 16x16x32 frags).
// LDS tiles [row][64 bf16] = 128B rows, 16B-slot XOR swizzle: slot ^= row&7.
// EPI 0: out [B][O][L].  EPI 1: v_samp [(b*8+o/32)][l][o%32].
// ---------------------------------------------------------------------------
template<int EPI>
__global__ __launch_bounds__(256, 2)
void gemm_bf16(const float* __restrict__ X, const float* __restrict__ Wm,
               const float* __restrict__ bias, float* __restrict__ out)
{
    __shared__ uint32_t a_s[128 * 32];   // 16 KB
    __shared__ uint32_t b_s[128 * 32];   // 16 KB

    const int nb = blockIdx.x;           // 0..255 (b*32 + l-tile)
    const int b  = nb >> 5;
    const int lb = nb & 31;
    const int ob = blockIdx.y;           // 0..1
    const int t  = threadIdx.x;
    const int lane = t & 63;
    const int wv = t >> 6;
    const int wm = wv >> 1, wn = wv & 1;

    const int a_f4 = t & 15;
    const int a_r0 = t >> 4;
    const int b_kb = t & 7;
    const int b_l0 = t >> 3;             // 0..31

    const float* Ap = Wm + (size_t)(ob * 128 + a_r0) * CC + a_f4 * 4;
    const float* Bp = X + ((size_t)b * CC + b_kb * 8) * LL + lb * 128 + b_l0 * 4;

    f32x4 acc[4][4];
#pragma unroll
    for (int i = 0; i < 4; ++i)
#pragma unroll
        for (int j = 0; j < 4; ++j) acc[i][j] = (f32x4)0.0f;

    for (int kc = 0; kc < 4; ++kc) {
        float4 av[8], bv[8];
        const float* ap = Ap + kc * 64;
        const float* bp = Bp + (size_t)(kc * 64) * LL;
#pragma unroll
        for (int i = 0; i < 8; ++i)
            av[i] = *(const float4*)(ap + (size_t)i * 16 * CC);
#pragma unroll
        for (int i = 0; i < 8; ++i)
            bv[i] = *(const float4*)(bp + (size_t)i * LL);

#pragma unroll
        for (int i = 0; i < 8; ++i) {
            int r = a_r0 + i * 16;
            uint32_t lo = pk_bf16(av[i].x, av[i].y);
            uint32_t hi = pk_bf16(av[i].z, av[i].w);
            int slot = (a_f4 >> 1) ^ (r & 7);
            *(uint2*)&a_s[r * 32 + (slot << 2) + ((a_f4 & 1) << 1)] =
                make_uint2(lo, hi);
        }
#pragma unroll
        for (int j = 0; j < 4; ++j) {
            int l = b_l0 * 4 + j;
            uint32_t w0 = pk_bf16(((const float*)&bv[0])[j], ((const float*)&bv[1])[j]);
            uint32_t w1 = pk_bf16(((const float*)&bv[2])[j], ((const float*)&bv[3])[j]);
            uint32_t w2 = pk_bf16(((const float*)&bv[4])[j], ((const float*)&bv[5])[j]);
            uint32_t w3 = pk_bf16(((const float*)&bv[6])[j], ((const float*)&bv[7])[j]);
            int slot = b_kb ^ (l & 7);
            *(uint4*)&b_s[l * 32 + (slot << 2)] = make_uint4(w0, w1, w2, w3);
        }
        __syncthreads();

#pragma unroll
        for (int ks = 0; ks < 2; ++ks) {
            int ag = ks * 4 + (lane >> 4);
            short8 af[4], bf[4];
#pragma unroll
            for (int mf = 0; mf < 4; ++mf) {
                int r = wm * 64 + mf * 16 + (lane & 15);
                af[mf] = *(const short8*)&a_s[r * 32 + ((ag ^ (r & 7)) << 2)];
            }
#pragma unroll
            for (int nf = 0; nf < 4; ++nf) {
                int r = wn * 64 + nf * 16 + (lane & 15);
                bf[nf] = *(const short8*)&b_s[r * 32 + ((ag ^ (r & 7)) << 2)];
            }
#pragma unroll
            for (int mf = 0; mf < 4; ++mf)
#pragma unroll
                for (int nf = 0; nf < 4; ++nf)
                    acc[mf][nf] = __builtin_amdgcn_mfma_f32_16x16x32_bf16(
                        af[mf], bf[nf], acc[mf][nf], 0, 0, 0);
        }
        __syncthreads();
    }

    const int l_base = lb * 128 + wn * 64 + (lane & 15);
    const int o_base = ob * 128 + wm * 64 + ((lane >> 4) << 2);
    if (EPI == 0) {
#pragma unroll
        for (int mf = 0; mf < 4; ++mf) {
            int o0 = o_base + mf * 16;
            float4 bs = *(const float4*)(bias + o0);
#pragma unroll
            for (int nf = 0; nf < 4; ++nf) {
                int l = l_base + nf * 16;
                float* op = out + ((size_t)b * CC + o0) * LL + l;
                op[(size_t)0 * LL] = acc[mf][nf][0] + bs.x;
                op[(size_t)1 * LL] = acc[mf][nf][1] + bs.y;
                op[(size_t)2 * LL] = acc[mf][nf][2] + bs.z;
                op[(size_t)3 * LL] = acc[mf][nf][3] + bs.w;
            }
        }
    } else {
#pragma unroll
        for (int mf = 0; mf < 4; ++mf) {
            int o0 = o_base + mf * 16;
            float4 bs = *(const float4*)(bias + o0);
            int a_h = o0 >> 5;
            int d0 = o0 & 31;
#pragma unroll
            for (int nf = 0; nf < 4; ++nf) {
                int l = l_base + nf * 16;
                float4 r = make_float4(acc[mf][nf][0] + bs.x, acc[mf][nf][1] + bs.y,
                                       acc[mf][nf][2] + bs.z, acc[mf][nf][3] + bs.w);
                *(float4*)(out + ((size_t)(b * AH + a_h) * LL + l) * DD + d0) = r;
            }
        }
    }
}

// ---------------------------------------------------------------------------
// fp32 GEMM (att/off heads: position-critical precision)
// ---------------------------------------------------------------------------
__global__ __launch_bounds__(256, 2)
void gemm_f32(const float* __restrict__ X, const float* __restrict__ Wm,
              const float* __restrict__ bias, float* __restrict__ out, int O)
{
    __shared__ float w_s[64][36];
    __shared__ float x_s[32][128];

    const int lb = blockIdx.x;
    const int ob = blockIdx.y;
    const int b  = blockIdx.z;
    const int t  = threadIdx.x;
    const int tx = t & 31;
    const int ty = t >> 5;
    const int l0 = tx * 4;
    const int o0 = ty * 8;

    float acc[8][4];
#pragma unroll
    for (int i = 0; i < 8; ++i)
#pragma unroll
        for (int j = 0; j < 4; ++j) acc[i][j] = 0.f;

    const float* Xb = X + (size_t)b * CC * LL + lb * 128;

    for (int k0 = 0; k0 < CC; k0 += 32) {
        {
            int o  = t >> 2;
            int cs = (t & 3) * 8;
            int og = ob * 64 + o;
            float4 v0, v1;
            if (og < O) {
                const float* wp = Wm + (size_t)og * CC + k0 + cs;
                v0 = *(const float4*)wp;
                v1 = *(const float4*)(wp + 4);
            } else {
                v0 = make_float4(0.f, 0.f, 0.f, 0.f);
                v1 = v0;
            }
            *(float4*)&w_s[o][cs]     = v0;
            *(float4*)&w_s[o][cs + 4] = v1;
        }
#pragma unroll
        for (int i = 0; i < 4; ++i) {
            int f4 = i * 256 + t;
            int kk = f4 >> 5;
            int l4 = f4 & 31;
            *(float4*)&x_s[kk][l4 * 4] =
                *(const float4*)(Xb + (size_t)(k0 + kk) * LL + l4 * 4);
        }
        __syncthreads();

#pragma unroll
        for (int ks = 0; ks < 32; ks += 4) {
            float4 xq[4];
#pragma unroll
            for (int k = 0; k < 4; ++k) xq[k] = *(const float4*)&x_s[ks + k][l0];
#pragma unroll
            for (int i = 0; i < 8; ++i) {
                float4 wq = *(const float4*)&w_s[o0 + i][ks];
                acc[i][0] += wq.x * xq[0].x; acc[i][1] += wq.x * xq[0].y;
                acc[i][2] += wq.x * xq[0].z; acc[i][3] += wq.x * xq[0].w;
                acc[i][0] += wq.y * xq[1].x; acc[i][1] += wq.y * xq[1].y;
                acc[i][2] += wq.y * xq[1].z; acc[i][3] += wq.y * xq[1].w;
                acc[i][0] += wq.z * xq[2].x; acc[i][1] += wq.z * xq[2].y;
                acc[i][2] += wq.z * xq[2].z; acc[i][3] += wq.z * xq[2].w;
                acc[i][0] += wq.w * xq[3].x; acc[i][1] += wq.w * xq[3].y;
                acc[i][2] += wq.w * xq[3].z; acc[i][3] += wq.w * xq[3].w;
            }
        }
        __syncthreads();
    }

    const int og0 = ob * 64 + o0;
    const int lg0 = lb * 128 + l0;
#pragma unroll
    for (int i = 0; i < 8; ++i) {
        int og = og0 + i;
        if (og < O) {
            float bs = bias[og];
            float4 r = make_float4(acc[i][0] + bs, acc[i][1] + bs,
                                   acc[i][2] + bs, acc[i][3] + bs);
            *(float4*)(out + ((size_t)b * O + og) * LL + lg0) = r;
        }
    }
}

// ---------------------------------------------------------------------------
// Fused softmax + offset->pos + bilinear sample + aggregation.
// 1-D grid of 4096 blocks; XCD-locality swizzle: all 64 l-tiles of one
// (b,a) image map to the same XCD (bid&7), images sequential within XCD.
// 4 threads per point, 8 channels each.
// ---------------------------------------------------------------------------
__global__ __launch_bounds__(256)
void sample_kernel(const float* __restrict__ v_samp,   // [(B*A)][L][32]
                   const float* __restrict__ log_att,  // [B][32][L]
                   const float* __restrict__ log_off,  // [B][64][L]
                   float* __restrict__ agg)            // [B][C][L]
{
    const int bid  = blockIdx.x;         // 0..4095
    const int xcd  = bid & 7;
    const int rest = bid >> 3;           // 0..511
    const int img  = rest >> 6;          // 0..7
    const int lt   = rest & 63;
    const int ba   = xcd * 8 + img;      // 0..63
    const int b = ba >> 3, a = ba & 7;

    const int t  = threadIdx.x;
    const int l  = lt * 64 + (t >> 2);
    const int d0 = (t & 3) * 8;

    // --- softmax over N=4 ---
    const float* la = log_att + ((size_t)b * 32 + a * 4) * LL + l;
    float e0 = la[0], e1 = la[(size_t)LL], e2 = la[(size_t)2 * LL], e3 = la[(size_t)3 * LL];
    float m = fmaxf(fmaxf(e0, e1), fmaxf(e2, e3));
    e0 = expf(e0 - m); e1 = expf(e1 - m); e2 = expf(e2 - m); e3 = expf(e3 - m);
    float inv = 1.0f / (e0 + e1 + e2 + e3);
    float attn[4] = {e0 * inv, e1 * inv, e2 * inv, e3 * inv};

    // --- positions ---
    const int gi = l >> 6, gj = l & 63;
    float ry = (gi + 0.5f) * (2.0f / 63.0f) - 1.0f;
    float rx = (gj + 0.5f) * (2.0f / 63.0f) - 1.0f;
    const float* lo = log_off + ((size_t)b * 64 + a * 8) * LL + l;
    float pyy[4], pxx[4];
#pragma unroll
    for (int n = 0; n < 4; ++n) {
        pyy[n] = ry + lo[(size_t)(n * 2 + 0) * LL];
        pxx[n] = rx + lo[(size_t)(n * 2 + 1) * LL];
    }

    float acc[8];
#pragma unroll
    for (int q = 0; q < 8; ++q) acc[q] = 0.f;

    const float* vb = v_samp + (size_t)ba * LL * DD;
#pragma unroll
    for (int n = 0; n < 4; ++n) {
        float y = (pyy[n] + 1.0f) * 0.5f * 63.0f;
        float x = (pxx[n] + 1.0f) * 0.5f * 63.0f;
        float yf = floorf(y), xf = floorf(x);
        int y0i = (int)yf, x0i = (int)xf;
        float fy = y - yf, fx = x - xf;
        float wts[4] = {(1.f - fy) * (1.f - fx), (1.f - fy) * fx,
                        fy * (1.f - fx),         fy * fx};
        int yy[4] = {y0i, y0i, y0i + 1, y0i + 1};
        int xx[4] = {x0i, x0i + 1, x0i, x0i + 1};
#pragma unroll
        for (int c2 = 0; c2 < 4; ++c2) {
            int yc = yy[c2], xc = xx[c2];
            if (yc >= 0 && yc < HH && xc >= 0 && xc < WW) {
                float w = attn[n] * wts[c2];
                const float* vp = vb + (size_t)(yc * WW + xc) * DD + d0;
                float4 v0 = *(const float4*)vp;
                float4 v1 = *(const float4*)(vp + 4);
                acc[0] += w * v0.x; acc[1] += w * v0.y;
                acc[2] += w * v0.z; acc[3] += w * v0.w;
                acc[4] += w * v1.x; acc[5] += w * v1.y;
                acc[6] += w * v1.z; acc[7] += w * v1.w;
            }
        }
    }
    float* ag = agg + ((size_t)b * CC + a * DD + d0) * LL + l;
#pragma unroll
    for (int q = 0; q < 8; ++q) ag[(size_t)q * LL] = acc[q];
}

extern "C" void kernel_launch(void* const* d_in, const int* in_sizes, int n_in,
                              void* d_out, int out_size, void* d_ws, size_t ws_size,
                              hipStream_t stream) {
    const float* x     = (const float*)d_in[0];
    const float* w_att = (const float*)d_in[1];
    const float* b_att = (const float*)d_in[2];
    const float* w_off = (const float*)d_in[3];
    const float* b_off = (const float*)d_in[4];
    const float* w_v   = (const float*)d_in[5];
    const float* b_v   = (const float*)d_in[6];
    const float* w_out = (const float*)d_in[7];
    const float* b_out = (const float*)d_in[8];
    float* out = (float*)d_out;

    float* ws      = (float*)d_ws;
    float* log_att = ws;                                  // B*32*L
    float* log_off = log_att + (size_t)BQ * 32 * LL;      // B*64*L
    float* agg     = log_off + (size_t)BQ * 64 * LL;      // B*C*L
    float* v_samp  = out;  // d_out reused as scratch for v (dead before final GEMM)

    dim3 blk(256);
    gemm_f32<<<dim3(32, 1, BQ), blk, 0, stream>>>(x, w_att, b_att, log_att, 32);
    gemm_f32<<<dim3(32, 1, BQ), blk, 0, stream>>>(x, w_off, b_off, log_off, 64);
    gemm_bf16<1><<<dim3(256, 2), blk, 0, stream>>>(x, w_v, b_v, v_samp);
    sample_kernel<<<dim3(4096), blk, 0, stream>>>(v_samp, log_att, log_off, agg);
    gemm_bf16<0><<<dim3(256, 2), blk, 0, stream>>>(agg, w_out, b_out, out);
}

// Round 4
// 99.198 us; speedup vs baseline: 2.3745x; 1.1862x over previous
//
#include <hip/hip_runtime.h>
#include <math.h>
#include <stdint.h>

#define BQ 8
#define CC 256
#define HH 64
#define WW 64
#define LL 4096
#define AH 8
#define DD 32

typedef __attribute__((ext_vector_type(4))) float f32x4;
typedef __attribute__((ext_vector_type(8))) short short8;

__device__ __forceinline__ uint32_t pk_bf16(float a, float b) {
    uint32_t r;
    asm("v_cvt_pk_bf16_f32 %0, %1, %2" : "=v"(r) : "v"(a), "v"(b));
    return r;
}
__device__ __forceinline__ float bf_lo(uint32_t u) { return __uint_as_float(u << 16); }
__device__ __forceinline__ float bf_hi(uint32_t u) { return __uint_as_float(u & 0xffff0000u); }

// ---------------- shared GEMM building blocks ----------------
// LDS tile layout (per buffer): 128 rows x 32 uint32 (64 bf16) = 16 KB.
// 16B slot s of row r stored at slot s^(r&7)  (XOR swizzle, conflict-free).

__device__ __forceinline__ void load8(float4 v[8], const float* p, size_t stride) {
#pragma unroll
    for (int i = 0; i < 8; ++i) v[i] = *(const float4*)(p + (size_t)i * stride);
}

// A: W rows (fp32, k-contig). thread t covers rows (t>>4)+i*16, k-offset (t&15)*4
__device__ __forceinline__ void writeA(const float4 av[8], uint32_t* as, int a_r0, int a_f4) {
#pragma unroll
    for (int i = 0; i < 8; ++i) {
        int r = a_r0 + i * 16;
        uint32_t lo = pk_bf16(av[i].x, av[i].y);
        uint32_t hi = pk_bf16(av[i].z, av[i].w);
        int slot = (a_f4 >> 1) ^ (r & 7);
        *(uint2*)&as[r * 32 + (slot << 2) + ((a_f4 & 1) << 1)] = make_uint2(lo, hi);
    }
}

// B from X fp32 [k][l]: transpose-stage. thread t: k-block t&7, l-group t>>3
__device__ __forceinline__ void writeB_x(const float4 bv[8], uint32_t* bs, int b_kb, int b_l0) {
#pragma unroll
    for (int j = 0; j < 4; ++j) {
        int l = b_l0 * 4 + j;
        uint32_t w0 = pk_bf16(((const float*)&bv[0])[j], ((const float*)&bv[1])[j]);
        uint32_t w1 = pk_bf16(((const float*)&bv[2])[j], ((const float*)&bv[3])[j]);
        uint32_t w2 = pk_bf16(((const float*)&bv[4])[j], ((const float*)&bv[5])[j]);
        uint32_t w3 = pk_bf16(((const float*)&bv[6])[j], ((const float*)&bv[7])[j]);
        int slot = b_kb ^ (l & 7);
        *(uint4*)&bs[l * 32 + (slot << 2)] = make_uint4(w0, w1, w2, w3);
    }
}

__device__ __forceinline__ void compute_tile(const uint32_t* as, const uint32_t* bs,
                                             f32x4 acc[4][4], int lane, int wm, int wn) {
#pragma unroll
    for (int ks = 0; ks < 2; ++ks) {
        int ag = ks * 4 + (lane >> 4);
        short8 af[4], bf[4];
#pragma unroll
        for (int mf = 0; mf < 4; ++mf) {
            int r = wm * 64 + mf * 16 + (lane & 15);
            af[mf] = *(const short8*)&as[r * 32 + ((ag ^ (r & 7)) << 2)];
        }
#pragma unroll
        for (int nf = 0; nf < 4; ++nf) {
            int r = wn * 64 + nf * 16 + (lane & 15);
            bf[nf] = *(const short8*)&bs[r * 32 + ((ag ^ (r & 7)) << 2)];
        }
#pragma unroll
        for (int mf = 0; mf < 4; ++mf)
#pragma unroll
            for (int nf = 0; nf < 4; ++nf)
                acc[mf][nf] = __builtin_amdgcn_mfma_f32_16x16x32_bf16(
                    af[mf], bf[nf], acc[mf][nf], 0, 0, 0);
    }
}

// ---------------------------------------------------------------------------
// gemm_v: v[b][o][l] = sum_k Wv[o][k]*X[b][k][l]+bias -> bf16 [(b*8+o/32)][l][o%32]
// 128x128 tile, BK=64, double-buffered pipeline.
// ---------------------------------------------------------------------------
__global__ __launch_bounds__(256, 2)
void gemm_v(const float* __restrict__ X, const float* __restrict__ Wm,
            const float* __restrict__ bias, uint16_t* __restrict__ vout)
{
    __shared__ uint32_t a_s[2][128 * 32];
    __shared__ uint32_t b_s[2][128 * 32];

    const int nb = blockIdx.x;
    const int b  = nb >> 5;
    const int lb = nb & 31;
    const int ob = blockIdx.y;
    const int t  = threadIdx.x;
    const int lane = t & 63;
    const int wv = t >> 6;
    const int wm = wv >> 1, wn = wv & 1;

    const int a_f4 = t & 15, a_r0 = t >> 4;
    const int b_kb = t & 7,  b_l0 = t >> 3;

    const float* Ap = Wm + (size_t)(ob * 128 + a_r0) * CC + a_f4 * 4;
    const float* Bp = X + ((size_t)b * CC + b_kb * 8) * LL + lb * 128 + b_l0 * 4;

    f32x4 acc[4][4];
#pragma unroll
    for (int i = 0; i < 4; ++i)
#pragma unroll
        for (int j = 0; j < 4; ++j) acc[i][j] = (f32x4)0.0f;

    float4 av[8], bv[8];
    load8(av, Ap, (size_t)16 * CC);
    load8(bv, Bp, (size_t)LL);
    writeA(av, a_s[0], a_r0, a_f4);
    writeB_x(bv, b_s[0], b_kb, b_l0);
    __syncthreads();

    for (int kc = 0; kc < 4; ++kc) {
        const int cur = kc & 1;
        if (kc < 3) {
            load8(av, Ap + (kc + 1) * 64, (size_t)16 * CC);
            load8(bv, Bp + (size_t)(kc + 1) * 64 * LL, (size_t)LL);
        }
        compute_tile(a_s[cur], b_s[cur], acc, lane, wm, wn);
        if (kc < 3) {
            writeA(av, a_s[cur ^ 1], a_r0, a_f4);
            writeB_x(bv, b_s[cur ^ 1], b_kb, b_l0);
            __syncthreads();
        }
    }

    const int l_base = lb * 128 + wn * 64 + (lane & 15);
    const int o_base = ob * 128 + wm * 64 + ((lane >> 4) << 2);
#pragma unroll
    for (int mf = 0; mf < 4; ++mf) {
        int o0 = o_base + mf * 16;
        float4 bs = *(const float4*)(bias + o0);
        int a_h = o0 >> 5;
        int d0 = o0 & 31;
#pragma unroll
        for (int nf = 0; nf < 4; ++nf) {
            int l = l_base + nf * 16;
            uint32_t p0 = pk_bf16(acc[mf][nf][0] + bs.x, acc[mf][nf][1] + bs.y);
            uint32_t p1 = pk_bf16(acc[mf][nf][2] + bs.z, acc[mf][nf][3] + bs.w);
            *(uint2*)(vout + ((size_t)(b * AH + a_h) * LL + l) * DD + d0) =
                make_uint2(p0, p1);
        }
    }
}

// ---------------------------------------------------------------------------
// gemm_out: y[b][o][l] = sum_c Wout[o][c]*agg_bf16[b][l][c] + bias, fp32 out.
// B-tiles are contiguous l-major bf16 rows: no transpose, no cvt.
// ---------------------------------------------------------------------------
__global__ __launch_bounds__(256, 2)
void gemm_out(const uint16_t* __restrict__ Agg, const float* __restrict__ Wm,
              const float* __restrict__ bias, float* __restrict__ out)
{
    __shared__ uint32_t a_s[2][128 * 32];
    __shared__ uint32_t b_s[2][128 * 32];

    const int nb = blockIdx.x;
    const int b  = nb >> 5;
    const int lb = nb & 31;
    const int ob = blockIdx.y;
    const int t  = threadIdx.x;
    const int lane = t & 63;
    const int wv = t >> 6;
    const int wm = wv >> 1, wn = wv & 1;

    const int a_f4 = t & 15, a_r0 = t >> 4;
    const int br = t >> 1;          // B row (l within tile), 0..127
    const int bh = t & 1;           // half (32 bf16) of the 64-k row

    const float* Ap = Wm + (size_t)(ob * 128 + a_r0) * CC + a_f4 * 4;
    const uint16_t* Bp = Agg + ((size_t)b * LL + lb * 128 + br) * CC + bh * 32;

    f32x4 acc[4][4];
#pragma unroll
    for (int i = 0; i < 4; ++i)
#pragma unroll
        for (int j = 0; j < 4; ++j) acc[i][j] = (f32x4)0.0f;

    float4 av[8];
    uint4 bq[4];
    load8(av, Ap, (size_t)16 * CC);
#pragma unroll
    for (int j = 0; j < 4; ++j) bq[j] = *(const uint4*)(Bp + j * 8);
    writeA(av, a_s[0], a_r0, a_f4);
#pragma unroll
    for (int j = 0; j < 4; ++j)
        *(uint4*)&b_s[0][br * 32 + ((((bh << 2) + j) ^ (br & 7)) << 2)] = bq[j];
    __syncthreads();

    for (int kc = 0; kc < 4; ++kc) {
        const int cur = kc & 1;
        if (kc < 3) {
            load8(av, Ap + (kc + 1) * 64, (size_t)16 * CC);
#pragma unroll
            for (int j = 0; j < 4; ++j)
                bq[j] = *(const uint4*)(Bp + (kc + 1) * 64 + j * 8);
        }
        compute_tile(a_s[cur], b_s[cur], acc, lane, wm, wn);
        if (kc < 3) {
            writeA(av, a_s[cur ^ 1], a_r0, a_f4);
#pragma unroll
            for (int j = 0; j < 4; ++j)
                *(uint4*)&b_s[cur ^ 1][br * 32 + ((((bh << 2) + j) ^ (br & 7)) << 2)] = bq[j];
            __syncthreads();
        }
    }

    const int l_base = lb * 128 + wn * 64 + (lane & 15);
    const int o_base = ob * 128 + wm * 64 + ((lane >> 4) << 2);
#pragma unroll
    for (int mf = 0; mf < 4; ++mf) {
        int o0 = o_base + mf * 16;
        float4 bs = *(const float4*)(bias + o0);
#pragma unroll
        for (int nf = 0; nf < 4; ++nf) {
            int l = l_base + nf * 16;
            float* op = out + ((size_t)b * CC + o0) * LL + l;
            op[(size_t)0 * LL] = acc[mf][nf][0] + bs.x;
            op[(size_t)1 * LL] = acc[mf][nf][1] + bs.y;
            op[(size_t)2 * LL] = acc[mf][nf][2] + bs.z;
            op[(size_t)3 * LL] = acc[mf][nf][3] + bs.w;
        }
    }
}

// ---------------------------------------------------------------------------
// fp32 GEMM (att/off heads: position-critical precision)
// ---------------------------------------------------------------------------
__global__ __launch_bounds__(256, 2)
void gemm_f32(const float* __restrict__ X, const float* __restrict__ Wm,
              const float* __restrict__ bias, float* __restrict__ out, int O)
{
    __shared__ float w_s[64][36];
    __shared__ float x_s[32][128];

    const int lb = blockIdx.x;
    const int ob = blockIdx.y;
    const int b  = blockIdx.z;
    const int t  = threadIdx.x;
    const int tx = t & 31;
    const int ty = t >> 5;
    const int l0 = tx * 4;
    const int o0 = ty * 8;

    float acc[8][4];
#pragma unroll
    for (int i = 0; i < 8; ++i)
#pragma unroll
        for (int j = 0; j < 4; ++j) acc[i][j] = 0.f;

    const float* Xb = X + (size_t)b * CC * LL + lb * 128;

    for (int k0 = 0; k0 < CC; k0 += 32) {
        {
            int o  = t >> 2;
            int cs = (t & 3) * 8;
            int og = ob * 64 + o;
            float4 v0, v1;
            if (og < O) {
                const float* wp = Wm + (size_t)og * CC + k0 + cs;
                v0 = *(const float4*)wp;
                v1 = *(const float4*)(wp + 4);
            } else {
                v0 = make_float4(0.f, 0.f, 0.f, 0.f);
                v1 = v0;
            }
            *(float4*)&w_s[o][cs]     = v0;
            *(float4*)&w_s[o][cs + 4] = v1;
        }
#pragma unroll
        for (int i = 0; i < 4; ++i) {
            int f4 = i * 256 + t;
            int kk = f4 >> 5;
            int l4 = f4 & 31;
            *(float4*)&x_s[kk][l4 * 4] =
                *(const float4*)(Xb + (size_t)(k0 + kk) * LL + l4 * 4);
        }
        __syncthreads();

#pragma unroll
        for (int ks = 0; ks < 32; ks += 4) {
            float4 xq[4];
#pragma unroll
            for (int k = 0; k < 4; ++k) xq[k] = *(const float4*)&x_s[ks + k][l0];
#pragma unroll
            for (int i = 0; i < 8; ++i) {
                float4 wq = *(const float4*)&w_s[o0 + i][ks];
                acc[i][0] += wq.x * xq[0].x; acc[i][1] += wq.x * xq[0].y;
                acc[i][2] += wq.x * xq[0].z; acc[i][3] += wq.x * xq[0].w;
                acc[i][0] += wq.y * xq[1].x; acc[i][1] += wq.y * xq[1].y;
                acc[i][2] += wq.y * xq[1].z; acc[i][3] += wq.y * xq[1].w;
                acc[i][0] += wq.z * xq[2].x; acc[i][1] += wq.z * xq[2].y;
                acc[i][2] += wq.z * xq[2].z; acc[i][3] += wq.z * xq[2].w;
                acc[i][0] += wq.w * xq[3].x; acc[i][1] += wq.w * xq[3].y;
                acc[i][2] += wq.w * xq[3].z; acc[i][3] += wq.w * xq[3].w;
            }
        }
        __syncthreads();
    }

    const int og0 = ob * 64 + o0;
    const int lg0 = lb * 128 + l0;
#pragma unroll
    for (int i = 0; i < 8; ++i) {
        int og = og0 + i;
        if (og < O) {
            float bs = bias[og];
            float4 r = make_float4(acc[i][0] + bs, acc[i][1] + bs,
                                   acc[i][2] + bs, acc[i][3] + bs);
            *(float4*)(out + ((size_t)b * O + og) * LL + lg0) = r;
        }
    }
}

// ---------------------------------------------------------------------------
// Fused softmax + offsets + bilinear sample + aggregation.
// v is bf16 [(ba)][l][32]; agg written bf16 l-major [B][L][256].
// XCD-locality: batch b pinned to XCD (bid&7); heads/tiles sequential.
// ---------------------------------------------------------------------------
__global__ __launch_bounds__(256)
void sample_kernel(const uint16_t* __restrict__ v_samp,
                   const float* __restrict__ log_att,   // [B][32][L]
                   const float* __restrict__ log_off,   // [B][64][L]
                   uint16_t* __restrict__ agg)          // [B][L][256] bf16
{
    const int bid  = blockIdx.x;         // 0..4095
    const int xcd  = bid & 7;
    const int rest = bid >> 3;
    const int img  = rest >> 6;
    const int lt   = rest & 63;
    const int ba   = xcd * 8 + img;
    const int b = ba >> 3, a = ba & 7;

    const int t  = threadIdx.x;
    const int l  = lt * 64 + (t >> 2);
    const int d0 = (t & 3) * 8;

    // softmax over N=4
    const float* la = log_att + ((size_t)b * 32 + a * 4) * LL + l;
    float e0 = la[0], e1 = la[(size_t)LL], e2 = la[(size_t)2 * LL], e3 = la[(size_t)3 * LL];
    float m = fmaxf(fmaxf(e0, e1), fmaxf(e2, e3));
    e0 = expf(e0 - m); e1 = expf(e1 - m); e2 = expf(e2 - m); e3 = expf(e3 - m);
    float inv = 1.0f / (e0 + e1 + e2 + e3);
    float attn[4] = {e0 * inv, e1 * inv, e2 * inv, e3 * inv};

    const int gi = l >> 6, gj = l & 63;
    float ry = (gi + 0.5f) * (2.0f / 63.0f) - 1.0f;
    float rx = (gj + 0.5f) * (2.0f / 63.0f) - 1.0f;
    const float* lo = log_off + ((size_t)b * 64 + a * 8) * LL + l;
    float pyy[4], pxx[4];
#pragma unroll
    for (int n = 0; n < 4; ++n) {
        pyy[n] = ry + lo[(size_t)(n * 2 + 0) * LL];
        pxx[n] = rx + lo[(size_t)(n * 2 + 1) * LL];
    }

    float acc[8];
#pragma unroll
    for (int q = 0; q < 8; ++q) acc[q] = 0.f;

    const uint16_t* vb = v_samp + (size_t)ba * LL * DD + d0;
#pragma unroll
    for (int n = 0; n < 4; ++n) {
        float y = (pyy[n] + 1.0f) * 0.5f * 63.0f;
        float x = (pxx[n] + 1.0f) * 0.5f * 63.0f;
        float yf = floorf(y), xf = floorf(x);
        int y0i = (int)yf, x0i = (int)xf;
        float fy = y - yf, fx = x - xf;
        float wts[4] = {(1.f - fy) * (1.f - fx), (1.f - fy) * fx,
                        fy * (1.f - fx),         fy * fx};
        int yy[4] = {y0i, y0i, y0i + 1, y0i + 1};
        int xx[4] = {x0i, x0i + 1, x0i, x0i + 1};
#pragma unroll
        for (int c2 = 0; c2 < 4; ++c2) {
            int yc = yy[c2], xc = xx[c2];
            if (yc >= 0 && yc < HH && xc >= 0 && xc < WW) {
                float w = attn[n] * wts[c2];
                uint4 rv = *(const uint4*)(vb + (size_t)(yc * WW + xc) * DD);
                acc[0] += w * bf_lo(rv.x); acc[1] += w * bf_hi(rv.x);
                acc[2] += w * bf_lo(rv.y); acc[3] += w * bf_hi(rv.y);
                acc[4] += w * bf_lo(rv.z); acc[5] += w * bf_hi(rv.z);
                acc[6] += w * bf_lo(rv.w); acc[7] += w * bf_hi(rv.w);
            }
        }
    }
    uint32_t p0 = pk_bf16(acc[0], acc[1]);
    uint32_t p1 = pk_bf16(acc[2], acc[3]);
    uint32_t p2 = pk_bf16(acc[4], acc[5]);
    uint32_t p3 = pk_bf16(acc[6], acc[7]);
    *(uint4*)(agg + ((size_t)b * LL + l) * CC + a * DD + d0) =
        make_uint4(p0, p1, p2, p3);
}

extern "C" void kernel_launch(void* const* d_in, const int* in_sizes, int n_in,
                              void* d_out, int out_size, void* d_ws, size_t ws_size,
                              hipStream_t stream) {
    const float* x     = (const float*)d_in[0];
    const float* w_att = (const float*)d_in[1];
    const float* b_att = (const float*)d_in[2];
    const float* w_off = (const float*)d_in[3];
    const float* b_off = (const float*)d_in[4];
    const float* w_v   = (const float*)d_in[5];
    const float* b_v   = (const float*)d_in[6];
    const float* w_out = (const float*)d_in[7];
    const float* b_out = (const float*)d_in[8];
    float* out = (float*)d_out;

    float* ws      = (float*)d_ws;
    float* log_att = ws;                                  // B*32*L f32
    float* log_off = log_att + (size_t)BQ * 32 * LL;      // B*64*L f32
    uint16_t* agg  = (uint16_t*)(log_off + (size_t)BQ * 64 * LL);  // B*L*256 bf16
    uint16_t* v_samp = (uint16_t*)d_out;  // d_out reused: v bf16 (16.7MB < 33.5MB),
                                          // dead before gemm_out writes fp32 out

    dim3 blk(256);
    gemm_f32<<<dim3(32, 1, BQ), blk, 0, stream>>>(x, w_att, b_att, log_att, 32);
    gemm_f32<<<dim3(32, 1, BQ), blk, 0, stream>>>(x, w_off, b_off, log_off, 64);
    gemm_v<<<dim3(256, 2), blk, 0, stream>>>(x, w_v, b_v, v_samp);
    sample_kernel<<<dim3(4096), blk, 0, stream>>>(v_samp, log_att, log_off, agg);
    gemm_out<<<dim3(256, 2), blk, 0, stream>>>(agg, w_out, b_out, out);
}

// Round 5
// 67.135 us; speedup vs baseline: 3.5084x; 1.4776x over previous
//
#include <hip/hip_runtime.h>
#include <math.h>
#include <stdint.h>

#define BQ 8
#define CC 256
#define HH 64
#define WW 64
#define LL 4096
#define AH 8
#define DD 32

typedef __attribute__((ext_vector_type(4))) float f32x4;
typedef __attribute__((ext_vector_type(8))) short short8;

__device__ __forceinline__ uint32_t pk_bf16(float a, float b) {
    uint32_t r;
    asm("v_cvt_pk_bf16_f32 %0, %1, %2" : "=v"(r) : "v"(a), "v"(b));
    return r;
}
__device__ __forceinline__ float bf_lo(uint32_t u) { return __uint_as_float(u << 16); }
__device__ __forceinline__ float bf_hi(uint32_t u) { return __uint_as_float(u & 0xffff0000u); }

// split (a,b) into bf16-hi pair and exact-residual bf16-lo pair
__device__ __forceinline__ void split2(float a, float b, uint32_t& hi, uint32_t& lo) {
    hi = pk_bf16(a, b);
    float ah = bf_lo(hi), bh = bf_hi(hi);
    lo = pk_bf16(a - ah, b - bh);
}

// ---------------- shared GEMM building blocks ----------------
// LDS tile: rows x 32 uint32 (64 bf16) = 128B rows.
// 16B slot s of row r stored at slot s^(r&7) (XOR swizzle, conflict-free).

__device__ __forceinline__ void load8(float4 v[8], const float* p, size_t stride) {
#pragma unroll
    for (int i = 0; i < 8; ++i) v[i] = *(const float4*)(p + (size_t)i * stride);
}

__device__ __forceinline__ void writeA(const float4 av[8], uint32_t* as, int a_r0, int a_f4) {
#pragma unroll
    for (int i = 0; i < 8; ++i) {
        int r = a_r0 + i * 16;
        uint32_t lo = pk_bf16(av[i].x, av[i].y);
        uint32_t hi = pk_bf16(av[i].z, av[i].w);
        int slot = (a_f4 >> 1) ^ (r & 7);
        *(uint2*)&as[r * 32 + (slot << 2) + ((a_f4 & 1) << 1)] = make_uint2(lo, hi);
    }
}

__device__ __forceinline__ void writeB_x(const float4 bv[8], uint32_t* bs, int b_kb, int b_l0) {
#pragma unroll
    for (int j = 0; j < 4; ++j) {
        int l = b_l0 * 4 + j;
        uint32_t w0 = pk_bf16(((const float*)&bv[0])[j], ((const float*)&bv[1])[j]);
        uint32_t w1 = pk_bf16(((const float*)&bv[2])[j], ((const float*)&bv[3])[j]);
        uint32_t w2 = pk_bf16(((const float*)&bv[4])[j], ((const float*)&bv[5])[j]);
        uint32_t w3 = pk_bf16(((const float*)&bv[6])[j], ((const float*)&bv[7])[j]);
        int slot = b_kb ^ (l & 7);
        *(uint4*)&bs[l * 32 + (slot << 2)] = make_uint4(w0, w1, w2, w3);
    }
}

__device__ __forceinline__ void compute_tile(const uint32_t* as, const uint32_t* bs,
                                             f32x4 acc[4][4], int lane, int wm, int wn) {
#pragma unroll
    for (int ks = 0; ks < 2; ++ks) {
        int ag = ks * 4 + (lane >> 4);
        short8 af[4], bf[4];
#pragma unroll
        for (int mf = 0; mf < 4; ++mf) {
            int r = wm * 64 + mf * 16 + (lane & 15);
            af[mf] = *(const short8*)&as[r * 32 + ((ag ^ (r & 7)) << 2)];
        }
#pragma unroll
        for (int nf = 0; nf < 4; ++nf) {
            int r = wn * 64 + nf * 16 + (lane & 15);
            bf[nf] = *(const short8*)&bs[r * 32 + ((ag ^ (r & 7)) << 2)];
        }
#pragma unroll
        for (int mf = 0; mf < 4; ++mf)
#pragma unroll
            for (int nf = 0; nf < 4; ++nf)
                acc[mf][nf] = __builtin_amdgcn_mfma_f32_16x16x32_bf16(
                    af[mf], bf[nf], acc[mf][nf], 0, 0, 0);
    }
}

// ---------------------------------------------------------------------------
// gemm_attoff: logits[b][o][l], o in [0,96): rows 0..31 = att (w_att),
// rows 32..95 = off (w_off). Split-bf16 MFMA (xh*wh + xh*wl + xl*wh) for
// fp32-class precision. 96x64 tile, BK=64, dbuf, 4 waves (2m x 2n).
// ---------------------------------------------------------------------------
__global__ __launch_bounds__(256, 2)
void gemm_attoff(const float* __restrict__ X,
                 const float* __restrict__ w_att, const float* __restrict__ w_off,
                 const float* __restrict__ b_att, const float* __restrict__ b_off,
                 float* __restrict__ outbuf)    // [B][96][L] fp32
{
    __shared__ uint32_t ah_s[2][96 * 32];
    __shared__ uint32_t al_s[2][96 * 32];
    __shared__ uint32_t bh_s[2][64 * 32];
    __shared__ uint32_t bl_s[2][64 * 32];

    const int lb = blockIdx.x;       // 0..63, l-tile of 64
    const int b  = blockIdx.y;
    const int t  = threadIdx.x;
    const int lane = t & 63;
    const int wv = t >> 6;
    const int wm = wv >> 1, wn = wv & 1;

    const int tr   = t >> 4;         // 0..15
    const int a_f4 = t & 15;         // float4 slot in 64-k row
    const int b_kb = t & 7;
    const int b_l0 = t >> 3;         // 0..31

    const float* Bp = X + ((size_t)b * CC + b_kb * 8) * LL + lb * 64 + b_l0 * 2;

    f32x4 acc[3][2];
#pragma unroll
    for (int i = 0; i < 3; ++i)
#pragma unroll
        for (int j = 0; j < 2; ++j) acc[i][j] = (f32x4)0.0f;

    float4 av[6];
    float2 bv[8];

    auto loadT = [&](int kc) {
#pragma unroll
        for (int i = 0; i < 6; ++i) {
            int r = i * 16 + tr;
            const float* wp = (i < 2) ? (w_att + (size_t)r * CC)
                                      : (w_off + (size_t)(r - 32) * CC);
            av[i] = *(const float4*)(wp + kc * 64 + a_f4 * 4);
        }
#pragma unroll
        for (int m = 0; m < 8; ++m)
            bv[m] = *(const float2*)(Bp + (size_t)(kc * 64 + m) * LL);
    };

    auto writeT = [&](int buf) {
#pragma unroll
        for (int i = 0; i < 6; ++i) {
            int r = i * 16 + tr;
            uint32_t h0, q0, h1, q1;
            split2(av[i].x, av[i].y, h0, q0);
            split2(av[i].z, av[i].w, h1, q1);
            int idx = r * 32 + (((a_f4 >> 1) ^ (r & 7)) << 2) + ((a_f4 & 1) << 1);
            *(uint2*)&ah_s[buf][idx] = make_uint2(h0, h1);
            *(uint2*)&al_s[buf][idx] = make_uint2(q0, q1);
        }
#pragma unroll
        for (int j = 0; j < 2; ++j) {
            int l = b_l0 * 2 + j;
            uint32_t h[4], q[4];
#pragma unroll
            for (int p = 0; p < 4; ++p) {
                float e0 = j ? bv[2 * p].y     : bv[2 * p].x;
                float e1 = j ? bv[2 * p + 1].y : bv[2 * p + 1].x;
                split2(e0, e1, h[p], q[p]);
            }
            int idx = l * 32 + ((b_kb ^ (l & 7)) << 2);
            *(uint4*)&bh_s[buf][idx] = make_uint4(h[0], h[1], h[2], h[3]);
            *(uint4*)&bl_s[buf][idx] = make_uint4(q[0], q[1], q[2], q[3]);
        }
    };

    auto computeT = [&](int buf) {
#pragma unroll
        for (int ks = 0; ks < 2; ++ks) {
            int ag = ks * 4 + (lane >> 4);
            short8 afh[3], afl[3], bfh[2], bfl[2];
#pragma unroll
            for (int mf = 0; mf < 3; ++mf) {
                int r = wm * 48 + mf * 16 + (lane & 15);
                int off = r * 32 + ((ag ^ (r & 7)) << 2);
                afh[mf] = *(const short8*)&ah_s[buf][off];
                afl[mf] = *(const short8*)&al_s[buf][off];
            }
#pragma unroll
            for (int nf = 0; nf < 2; ++nf) {
                int r = wn * 32 + nf * 16 + (lane & 15);
                int off = r * 32 + ((ag ^ (r & 7)) << 2);
                bfh[nf] = *(const short8*)&bh_s[buf][off];
                bfl[nf] = *(const short8*)&bl_s[buf][off];
            }
#pragma unroll
            for (int mf = 0; mf < 3; ++mf)
#pragma unroll
                for (int nf = 0; nf < 2; ++nf) {
                    acc[mf][nf] = __builtin_amdgcn_mfma_f32_16x16x32_bf16(
                        afh[mf], bfh[nf], acc[mf][nf], 0, 0, 0);
                    acc[mf][nf] = __builtin_amdgcn_mfma_f32_16x16x32_bf16(
                        afh[mf], bfl[nf], acc[mf][nf], 0, 0, 0);
                    acc[mf][nf] = __builtin_amdgcn_mfma_f32_16x16x32_bf16(
                        afl[mf], bfh[nf], acc[mf][nf], 0, 0, 0);
                }
        }
    };

    loadT(0);
    writeT(0);
    __syncthreads();
    for (int kc = 0; kc < 4; ++kc) {
        const int cur = kc & 1;
        if (kc < 3) loadT(kc + 1);
        computeT(cur);
        if (kc < 3) { writeT(cur ^ 1); __syncthreads(); }
    }

    const int l_base = lb * 64 + wn * 32 + (lane & 15);
    const int o_base = wm * 48 + ((lane >> 4) << 2);
#pragma unroll
    for (int mf = 0; mf < 3; ++mf) {
        int o0 = o_base + mf * 16;
        const float* bp = (o0 < 32) ? (b_att + o0) : (b_off + (o0 - 32));
        float4 bs = *(const float4*)bp;
#pragma unroll
        for (int nf = 0; nf < 2; ++nf) {
            int l = l_base + nf * 16;
            float* op = outbuf + ((size_t)b * 96 + o0) * LL + l;
            op[(size_t)0 * LL] = acc[mf][nf][0] + bs.x;
            op[(size_t)1 * LL] = acc[mf][nf][1] + bs.y;
            op[(size_t)2 * LL] = acc[mf][nf][2] + bs.z;
            op[(size_t)3 * LL] = acc[mf][nf][3] + bs.w;
        }
    }
}

// ---------------------------------------------------------------------------
// gemm_v: v[b][o][l] = sum_k Wv[o][k]*X[b][k][l]+bias -> bf16 [(b*8+o/32)][l][o%32]
// ---------------------------------------------------------------------------
__global__ __launch_bounds__(256, 2)
void gemm_v(const float* __restrict__ X, const float* __restrict__ Wm,
            const float* __restrict__ bias, uint16_t* __restrict__ vout)
{
    __shared__ uint32_t a_s[2][128 * 32];
    __shared__ uint32_t b_s[2][128 * 32];

    const int nb = blockIdx.x;
    const int b  = nb >> 5;
    const int lb = nb & 31;
    const int ob = blockIdx.y;
    const int t  = threadIdx.x;
    const int lane = t & 63;
    const int wv = t >> 6;
    const int wm = wv >> 1, wn = wv & 1;

    const int a_f4 = t & 15, a_r0 = t >> 4;
    const int b_kb = t & 7,  b_l0 = t >> 3;

    const float* Ap = Wm + (size_t)(ob * 128 + a_r0) * CC + a_f4 * 4;
    const float* Bp = X + ((size_t)b * CC + b_kb * 8) * LL + lb * 128 + b_l0 * 4;

    f32x4 acc[4][4];
#pragma unroll
    for (int i = 0; i < 4; ++i)
#pragma unroll
        for (int j = 0; j < 4; ++j) acc[i][j] = (f32x4)0.0f;

    float4 av[8], bv[8];
    load8(av, Ap, (size_t)16 * CC);
    load8(bv, Bp, (size_t)LL);
    writeA(av, a_s[0], a_r0, a_f4);
    writeB_x(bv, b_s[0], b_kb, b_l0);
    __syncthreads();

    for (int kc = 0; kc < 4; ++kc) {
        const int cur = kc & 1;
        if (kc < 3) {
            load8(av, Ap + (kc + 1) * 64, (size_t)16 * CC);
            load8(bv, Bp + (size_t)(kc + 1) * 64 * LL, (size_t)LL);
        }
        compute_tile(a_s[cur], b_s[cur], acc, lane, wm, wn);
        if (kc < 3) {
            writeA(av, a_s[cur ^ 1], a_r0, a_f4);
            writeB_x(bv, b_s[cur ^ 1], b_kb, b_l0);
            __syncthreads();
        }
    }

    const int l_base = lb * 128 + wn * 64 + (lane & 15);
    const int o_base = ob * 128 + wm * 64 + ((lane >> 4) << 2);
#pragma unroll
    for (int mf = 0; mf < 4; ++mf) {
        int o0 = o_base + mf * 16;
        float4 bs = *(const float4*)(bias + o0);
        int a_h = o0 >> 5;
        int d0 = o0 & 31;
#pragma unroll
        for (int nf = 0; nf < 4; ++nf) {
            int l = l_base + nf * 16;
            uint32_t p0 = pk_bf16(acc[mf][nf][0] + bs.x, acc[mf][nf][1] + bs.y);
            uint32_t p1 = pk_bf16(acc[mf][nf][2] + bs.z, acc[mf][nf][3] + bs.w);
            *(uint2*)(vout + ((size_t)(b * AH + a_h) * LL + l) * DD + d0) =
                make_uint2(p0, p1);
        }
    }
}

// ---------------------------------------------------------------------------
// gemm_out: y[b][o][l] = sum_c Wout[o][c]*agg_bf16[b][l][c] + bias, fp32 out.
// ---------------------------------------------------------------------------
__global__ __launch_bounds__(256, 2)
void gemm_out(const uint16_t* __restrict__ Agg, const float* __restrict__ Wm,
              const float* __restrict__ bias, float* __restrict__ out)
{
    __shared__ uint32_t a_s[2][128 * 32];
    __shared__ uint32_t b_s[2][128 * 32];

    const int nb = blockIdx.x;
    const int b  = nb >> 5;
    const int lb = nb & 31;
    const int ob = blockIdx.y;
    const int t  = threadIdx.x;
    const int lane = t & 63;
    const int wv = t >> 6;
    const int wm = wv >> 1, wn = wv & 1;

    const int a_f4 = t & 15, a_r0 = t >> 4;
    const int br = t >> 1;
    const int bh = t & 1;

    const float* Ap = Wm + (size_t)(ob * 128 + a_r0) * CC + a_f4 * 4;
    const uint16_t* Bp = Agg + ((size_t)b * LL + lb * 128 + br) * CC + bh * 32;

    f32x4 acc[4][4];
#pragma unroll
    for (int i = 0; i < 4; ++i)
#pragma unroll
        for (int j = 0; j < 4; ++j) acc[i][j] = (f32x4)0.0f;

    float4 av[8];
    uint4 bq[4];
    load8(av, Ap, (size_t)16 * CC);
#pragma unroll
    for (int j = 0; j < 4; ++j) bq[j] = *(const uint4*)(Bp + j * 8);
    writeA(av, a_s[0], a_r0, a_f4);
#pragma unroll
    for (int j = 0; j < 4; ++j)
        *(uint4*)&b_s[0][br * 32 + ((((bh << 2) + j) ^ (br & 7)) << 2)] = bq[j];
    __syncthreads();

    for (int kc = 0; kc < 4; ++kc) {
        const int cur = kc & 1;
        if (kc < 3) {
            load8(av, Ap + (kc + 1) * 64, (size_t)16 * CC);
#pragma unroll
            for (int j = 0; j < 4; ++j)
                bq[j] = *(const uint4*)(Bp + (kc + 1) * 64 + j * 8);
        }
        compute_tile(a_s[cur], b_s[cur], acc, lane, wm, wn);
        if (kc < 3) {
            writeA(av, a_s[cur ^ 1], a_r0, a_f4);
#pragma unroll
            for (int j = 0; j < 4; ++j)
                *(uint4*)&b_s[cur ^ 1][br * 32 + ((((bh << 2) + j) ^ (br & 7)) << 2)] = bq[j];
            __syncthreads();
        }
    }

    const int l_base = lb * 128 + wn * 64 + (lane & 15);
    const int o_base = ob * 128 + wm * 64 + ((lane >> 4) << 2);
#pragma unroll
    for (int mf = 0; mf < 4; ++mf) {
        int o0 = o_base + mf * 16;
        float4 bs = *(const float4*)(bias + o0);
#pragma unroll
        for (int nf = 0; nf < 4; ++nf) {
            int l = l_base + nf * 16;
            float* op = out + ((size_t)b * CC + o0) * LL + l;
            op[(size_t)0 * LL] = acc[mf][nf][0] + bs.x;
            op[(size_t)1 * LL] = acc[mf][nf][1] + bs.y;
            op[(size_t)2 * LL] = acc[mf][nf][2] + bs.z;
            op[(size_t)3 * LL] = acc[mf][nf][3] + bs.w;
        }
    }
}

// ---------------------------------------------------------------------------
// Fused softmax + offsets + bilinear sample + aggregation.
// logits: [B][96][L] (0..31 att, 32..95 off). v bf16 [(ba)][l][32].
// agg written bf16 l-major [B][L][256].
// ---------------------------------------------------------------------------
__global__ __launch_bounds__(256)
void sample_kernel(const uint16_t* __restrict__ v_samp,
                   const float* __restrict__ logits,
                   uint16_t* __restrict__ agg)
{
    const int bid  = blockIdx.x;         // 0..4095
    const int xcd  = bid & 7;
    const int rest = bid >> 3;
    const int img  = rest >> 6;
    const int lt   = rest & 63;
    const int ba   = xcd * 8 + img;
    const int b = ba >> 3, a = ba & 7;

    const int t  = threadIdx.x;
    const int l  = lt * 64 + (t >> 2);
    const int d0 = (t & 3) * 8;

    // softmax over N=4
    const float* la = logits + ((size_t)b * 96 + a * 4) * LL + l;
    float e0 = la[0], e1 = la[(size_t)LL], e2 = la[(size_t)2 * LL], e3 = la[(size_t)3 * LL];
    float m = fmaxf(fmaxf(e0, e1), fmaxf(e2, e3));
    e0 = expf(e0 - m); e1 = expf(e1 - m); e2 = expf(e2 - m); e3 = expf(e3 - m);
    float inv = 1.0f / (e0 + e1 + e2 + e3);
    float attn[4] = {e0 * inv, e1 * inv, e2 * inv, e3 * inv};

    const int gi = l >> 6, gj = l & 63;
    float ry = (gi + 0.5f) * (2.0f / 63.0f) - 1.0f;
    float rx = (gj + 0.5f) * (2.0f / 63.0f) - 1.0f;
    const float* lo = logits + ((size_t)b * 96 + 32 + a * 8) * LL + l;
    float pyy[4], pxx[4];
#pragma unroll
    for (int n = 0; n < 4; ++n) {
        pyy[n] = ry + lo[(size_t)(n * 2 + 0) * LL];
        pxx[n] = rx + lo[(size_t)(n * 2 + 1) * LL];
    }

    float acc[8];
#pragma unroll
    for (int q = 0; q < 8; ++q) acc[q] = 0.f;

    const uint16_t* vb = v_samp + (size_t)ba * LL * DD + d0;
#pragma unroll
    for (int n = 0; n < 4; ++n) {
        float y = (pyy[n] + 1.0f) * 0.5f * 63.0f;
        float x = (pxx[n] + 1.0f) * 0.5f * 63.0f;
        float yf = floorf(y), xf = floorf(x);
        int y0i = (int)yf, x0i = (int)xf;
        float fy = y - yf, fx = x - xf;
        float wts[4] = {(1.f - fy) * (1.f - fx), (1.f - fy) * fx,
                        fy * (1.f - fx),         fy * fx};
        int yy[4] = {y0i, y0i, y0i + 1, y0i + 1};
        int xx[4] = {x0i, x0i + 1, x0i, x0i + 1};
#pragma unroll
        for (int c2 = 0; c2 < 4; ++c2) {
            int yc = yy[c2], xc = xx[c2];
            if (yc >= 0 && yc < HH && xc >= 0 && xc < WW) {
                float w = attn[n] * wts[c2];
                uint4 rv = *(const uint4*)(vb + (size_t)(yc * WW + xc) * DD);
                acc[0] += w * bf_lo(rv.x); acc[1] += w * bf_hi(rv.x);
                acc[2] += w * bf_lo(rv.y); acc[3] += w * bf_hi(rv.y);
                acc[4] += w * bf_lo(rv.z); acc[5] += w * bf_hi(rv.z);
                acc[6] += w * bf_lo(rv.w); acc[7] += w * bf_hi(rv.w);
            }
        }
    }
    uint32_t p0 = pk_bf16(acc[0], acc[1]);
    uint32_t p1 = pk_bf16(acc[2], acc[3]);
    uint32_t p2 = pk_bf16(acc[4], acc[5]);
    uint32_t p3 = pk_bf16(acc[6], acc[7]);
    *(uint4*)(agg + ((size_t)b * LL + l) * CC + a * DD + d0) =
        make_uint4(p0, p1, p2, p3);
}

extern "C" void kernel_launch(void* const* d_in, const int* in_sizes, int n_in,
                              void* d_out, int out_size, void* d_ws, size_t ws_size,
                              hipStream_t stream) {
    const float* x     = (const float*)d_in[0];
    const float* w_att = (const float*)d_in[1];
    const float* b_att = (const float*)d_in[2];
    const float* w_off = (const float*)d_in[3];
    const float* b_off = (const float*)d_in[4];
    const float* w_v   = (const float*)d_in[5];
    const float* b_v   = (const float*)d_in[6];
    const float* w_out = (const float*)d_in[7];
    const float* b_out = (const float*)d_in[8];
    float* out = (float*)d_out;

    float* ws      = (float*)d_ws;
    float* logits  = ws;                                   // B*96*L f32
    uint16_t* agg  = (uint16_t*)(logits + (size_t)BQ * 96 * LL);  // B*L*256 bf16
    uint16_t* v_samp = (uint16_t*)d_out;  // d_out reused: v bf16 (16.7MB < 33.5MB),
                                          // dead before gemm_out writes fp32 out

    dim3 blk(256);
    gemm_attoff<<<dim3(64, BQ), blk, 0, stream>>>(x, w_att, w_off, b_att, b_off, logits);
    gemm_v<<<dim3(256, 2), blk, 0, stream>>>(x, w_v, b_v, v_samp);
    sample_kernel<<<dim3(4096), blk, 0, stream>>>(v_samp, logits, agg);
    gemm_out<<<dim3(256, 2), blk, 0, stream>>>(agg, w_out, b_out, out);
}